// Round 10
// baseline (18.965 us; speedup 1.0000x reference)
//
#include <hip/hip_runtime.h>

// Dihedral2Coord — one molecule per wave, TWO molecules pipelined per wave.
// final[m] = P_{m-3}(pos0[m]); P_k = B_0∘...∘B_k (LOCAL-frame step rotations;
// dihedrals are rigid-invariant so phi_k comes from pos0 alone).
// Pipeline: load A+B heads at t0 -> scan/emit/store A (B loads in flight) ->
// issue B tails -> scan/emit/store B. Breaks the lockstep load->compute->store
// phase serialization identified from the R7 x6 measurement.

#define NK 128
#define NM 512
#define NMOL 4096
#define TPB 256
#define WPB 4        // waves per block
#define MPWAVE 2     // molecules per wave
// grid = NMOL / (WPB * MPWAVE) = 512

struct Aff { float qw, qx, qy, qz, tx, ty, tz; };

__device__ __forceinline__ void qrot(float qw, float qx, float qy, float qz,
                                     float vx, float vy, float vz,
                                     float& ox, float& oy, float& oz) {
    const float ux = qy*vz - qz*vy + qw*vx;
    const float uy = qz*vx - qx*vz + qw*vy;
    const float uz = qx*vy - qy*vx + qw*vz;
    ox = vx + 2.f*(qy*uz - qz*uy);
    oy = vy + 2.f*(qz*ux - qx*uz);
    oz = vz + 2.f*(qx*uy - qy*ux);
}

__device__ __forceinline__ Aff aff_compose(const Aff& Q, const Aff& P) {
    Aff r;
    r.qw = Q.qw*P.qw - Q.qx*P.qx - Q.qy*P.qy - Q.qz*P.qz;
    r.qx = Q.qw*P.qx + Q.qx*P.qw + Q.qy*P.qz - Q.qz*P.qy;
    r.qy = Q.qw*P.qy - Q.qx*P.qz + Q.qy*P.qw + Q.qz*P.qx;
    r.qz = Q.qw*P.qz + Q.qx*P.qy - Q.qy*P.qx + Q.qz*P.qw;
    float rx, ry, rz;
    qrot(Q.qw, Q.qx, Q.qy, Q.qz, P.tx, P.ty, P.tz, rx, ry, rz);
    r.tx = rx + Q.tx; r.ty = ry + Q.ty; r.tz = rz + Q.tz;
    return r;
}

__device__ __forceinline__ void qnorm(Aff& a) {
    const float r = rsqrtf(a.qw*a.qw + a.qx*a.qx + a.qy*a.qy + a.qz*a.qz);
    a.qw *= r; a.qx *= r; a.qy *= r; a.qz *= r;
}

// Step rotation about axis J->K by (theta + dihedral(I,J,K,L)), pivot J.
// (cphi,sphi) via the exactly-normalized identity: (n1 x n2) || jk, so
// dnn^2 + g^2/Ljk == L1*L2 -> no renormalization needed; copysign half-angle
// (robust at phi ~ pi, same as the validated path).
__device__ __forceinline__ Aff build_step(const float* a, float th) {
    const float ijx=a[3]-a[0], ijy=a[4]-a[1],  ijz=a[5]-a[2];
    const float jkx=a[6]-a[3], jky=a[7]-a[4],  jkz=a[8]-a[5];
    const float klx=a[9]-a[6], kly=a[10]-a[7], klz=a[11]-a[8];
    const float n1x=ijy*jkz-ijz*jky, n1y=ijz*jkx-ijx*jkz, n1z=ijx*jky-ijy*jkx;
    const float n2x=jky*klz-jkz*kly, n2y=jkz*klx-jkx*klz, n2z=jkx*kly-jky*klx;
    const float L1=n1x*n1x+n1y*n1y+n1z*n1z;
    const float L2=n2x*n2x+n2y*n2y+n2z*n2z;
    const float dnn=n1x*n2x+n1y*n2y+n1z*n2z;
    // g = (n2 x n1) . jk = |n1||n2| sin(phi) |jk|
    const float cxx=n2y*n1z-n2z*n1y, cxy=n2z*n1x-n2x*n1z, cxz=n2x*n1y-n2y*n1x;
    const float g  = cxx*jkx + cxy*jky + cxz*jkz;
    const float Ljk = jkx*jkx+jky*jky+jkz*jkz;
    const float ira = rsqrtf(fmaxf(Ljk, 1e-24f));
    const float r12 = rsqrtf(fmaxf(L1*L2, 1e-30f));
    const float cphi = dnn*r12;
    const float sphi = g*r12*ira;
    const float sth = __sinf(th), cth = __cosf(th);
    const float c = cth*cphi - sth*sphi;   // cos(theta+phi)
    const float s = sth*cphi + cth*sphi;   // sin(theta+phi)
    const float hc = sqrtf(fmaxf(0.f, 0.5f*(1.f + c)));
    const float hs = copysignf(sqrtf(fmaxf(0.f, 0.5f*(1.f - c))), s);
    const float hsa = hs*ira;
    Aff b;
    b.qw = hc; b.qx = jkx*hsa; b.qy = jky*hsa; b.qz = jkz*hsa;
    float rx, ry, rz;
    qrot(b.qw, b.qx, b.qy, b.qz, a[3], a[4], a[5], rx, ry, rz);
    b.tx = a[3]-rx; b.ty = a[4]-ry; b.tz = a[5]-rz;
    return b;
}

#define SHFL_AFF_UP(D, S, off)                                           \
    D.qw = __shfl_up(S.qw, off, 64); D.qx = __shfl_up(S.qx, off, 64);    \
    D.qy = __shfl_up(S.qy, off, 64); D.qz = __shfl_up(S.qz, off, 64);    \
    D.tx = __shfl_up(S.tx, off, 64); D.ty = __shfl_up(S.ty, off, 64);    \
    D.tz = __shfl_up(S.tz, off, 64);

// Full per-molecule phase: assumes head already staged into sA (this wave's
// slice); consumes prefetched tail registers. All wave-level, no barriers.
__device__ __forceinline__ void do_molecule(
    const int lane, float* __restrict__ sA, float* __restrict__ sO,
    float4* __restrict__ ob4, const float2 th2,
    const float4 Ta0, const float4 Ta1, const float4 Ta2,
    const float4 Tb0, const float4 Tb1, const float4 Tb2, const bool hasB)
{
    // lane k: atoms 2k..2k+4 (15 floats)
    float A[16];
    const float2* ap2 = (const float2*)&sA[lane * 6];
    #pragma unroll
    for (int i = 0; i < 7; ++i) { const float2 v = ap2[i]; A[2*i] = v.x; A[2*i+1] = v.y; }
    A[14] = sA[lane * 6 + 14];

    Aff Bev = build_step(&A[0], th2.x);   // B_{2k}
    Aff Bod = build_step(&A[3], th2.y);   // B_{2k+1}
    Aff S   = aff_compose(Bev, Bod);      // C_k

    // wave-inclusive scan: S -> P_{2k+1}
    #pragma unroll
    for (int off = 1; off < 64; off <<= 1) {
        Aff Q; SHFL_AFF_UP(Q, S, off);
        if (lane >= off) S = aff_compose(Q, S);
    }
    Aff E; SHFL_AFF_UP(E, S, 1);
    if (lane == 0) { E.qw = 1.f; E.qx = E.qy = E.qz = 0.f; E.tx = E.ty = E.tz = 0.f; }
    Aff Pe = aff_compose(E, Bev);         // P_{2k}
    qnorm(Pe); qnorm(S);

    // emit head atoms into sO
    {
        float ox, oy, oz;
        float* op = &sO[lane * 6 + 9];
        qrot(Pe.qw, Pe.qx, Pe.qy, Pe.qz, A[9], A[10], A[11], ox, oy, oz);
        op[0] = ox + Pe.tx; op[1] = oy + Pe.ty; op[2] = oz + Pe.tz;
        qrot(S.qw, S.qx, S.qy, S.qz, A[12], A[13], A[14], ox, oy, oz);
        op[3] = ox + S.tx;  op[4] = oy + S.ty;  op[5] = oz + S.tz;
    }
    if (lane < 9) sO[lane] = sA[lane];    // atoms 0..2 never move
    if (lane == 63) {                     // atom 131 = P_127(pos0[131])
        float ox, oy, oz;
        qrot(S.qw, S.qx, S.qy, S.qz, sA[393], sA[394], sA[395], ox, oy, oz);
        sO[393] = ox + S.tx; sO[394] = oy + S.ty; sO[395] = oz + S.tz;
    }

    // F = P_127 broadcast (register-only)
    Aff F;
    F.qw = __shfl(S.qw, 63, 64); F.qx = __shfl(S.qx, 63, 64);
    F.qy = __shfl(S.qy, 63, 64); F.qz = __shfl(S.qz, 63, 64);
    F.tx = __shfl(S.tx, 63, 64); F.ty = __shfl(S.ty, 63, 64);
    F.tz = __shfl(S.tz, 63, 64);
    const float f00 = 1.f - 2.f*(F.qy*F.qy + F.qz*F.qz);
    const float f01 = 2.f*(F.qx*F.qy - F.qw*F.qz);
    const float f02 = 2.f*(F.qx*F.qz + F.qw*F.qy);
    const float f10 = 2.f*(F.qx*F.qy + F.qw*F.qz);
    const float f11 = 1.f - 2.f*(F.qx*F.qx + F.qz*F.qz);
    const float f12 = 2.f*(F.qy*F.qz - F.qw*F.qx);
    const float f20 = 2.f*(F.qx*F.qz - F.qw*F.qy);
    const float f21 = 2.f*(F.qy*F.qz + F.qw*F.qx);
    const float f22 = 1.f - 2.f*(F.qx*F.qx + F.qy*F.qy);

    // store head (99 float4)
    const float4* sO4 = (const float4*)sO;
    ob4[lane] = sO4[lane];
    if (lane < 35) ob4[64 + lane] = sO4[64 + lane];

    // tail (atoms 132..511), data already in registers
    #define TAIL_EMIT(b, va, vb, vc)                                          \
    do {                                                                      \
        const float x0=va.x, y0=va.y, z0=va.z;                                \
        const float x1=va.w, y1=vb.x, z1=vb.y;                                \
        const float x2=vb.z, y2=vb.w, z2=vc.x;                                \
        const float x3=vc.y, y3=vc.z, z3=vc.w;                                \
        float4 o0, o1, o2;                                                    \
        o0.x = f00*x0+f01*y0+f02*z0+F.tx; o0.y = f10*x0+f11*y0+f12*z0+F.ty;   \
        o0.z = f20*x0+f21*y0+f22*z0+F.tz; o0.w = f00*x1+f01*y1+f02*z1+F.tx;   \
        o1.x = f10*x1+f11*y1+f12*z1+F.ty; o1.y = f20*x1+f21*y1+f22*z1+F.tz;   \
        o1.z = f00*x2+f01*y2+f02*z2+F.tx; o1.w = f10*x2+f11*y2+f12*z2+F.ty;   \
        o2.x = f20*x2+f21*y2+f22*z2+F.tz; o2.y = f00*x3+f01*y3+f02*z3+F.tx;   \
        o2.z = f10*x3+f11*y3+f12*z3+F.ty; o2.w = f20*x3+f21*y3+f22*z3+F.tz;   \
        ob4[(b)] = o0; ob4[(b)+1] = o1; ob4[(b)+2] = o2;                      \
    } while (0)

    TAIL_EMIT(99 + 3*lane, Ta0, Ta1, Ta2);
    if (hasB) TAIL_EMIT(99 + 3*(64 + lane), Tb0, Tb1, Tb2);
    #undef TAIL_EMIT
}

__global__ __launch_bounds__(TPB, 2) void dihedral_pipe2_kernel(
    const float* __restrict__ theta,  // (NMOL, NK)
    const float* __restrict__ pos0,   // (NMOL, NM, 3)
    float* __restrict__ out)          // (NMOL, NM, 3)
{
    const int tid  = threadIdx.x;
    const int lane = tid & 63;
    const int wid  = tid >> 6;
    const int molA = blockIdx.x * (WPB * MPWAVE) + wid;
    const int molB = molA + WPB;

    const float4* __restrict__ pbA = (const float4*)(pos0 + (size_t)molA * (NM*3));
    float4*       __restrict__ obA = (float4*)(out  + (size_t)molA * (NM*3));
    const float4* __restrict__ pbB = (const float4*)(pos0 + (size_t)molB * (NM*3));
    float4*       __restrict__ obB = (float4*)(out  + (size_t)molB * (NM*3));

    __shared__ float sA[WPB][400];   // per-wave slice, reused A then B
    __shared__ float sO[WPB][400];

    const bool hasB2 = (lane < 31);  // tail tasks 64..94

    // ---- t0 burst: A head+theta, B head+theta, A tails ----
    float4 hA0 = pbA[lane];
    float4 hA1; if (lane < 35) hA1 = pbA[64 + lane];
    const float2 thA = ((const float2*)(theta + (size_t)molA * NK))[lane];
    float4 hB0 = pbB[lane];
    float4 hB1; if (lane < 35) hB1 = pbB[64 + lane];
    const float2 thB = ((const float2*)(theta + (size_t)molB * NK))[lane];
    float4 TaA0, TaA1, TaA2, TbA0, TbA1, TbA2;
    { const int b = 99 + 3*lane; TaA0 = pbA[b]; TaA1 = pbA[b+1]; TaA2 = pbA[b+2]; }
    if (hasB2) { const int b = 99 + 3*(64 + lane); TbA0 = pbA[b]; TbA1 = pbA[b+1]; TbA2 = pbA[b+2]; }

    // ---- phase A ----
    float4* sA4 = (float4*)sA[wid];
    sA4[lane] = hA0;
    if (lane < 35) sA4[64 + lane] = hA1;
    do_molecule(lane, sA[wid], sO[wid], obA, thA, TaA0, TaA1, TaA2, TbA0, TbA1, TbA2, hasB2);

    // ---- issue B tails (cover their latency with B's scan) ----
    float4 TaB0, TaB1, TaB2, TbB0, TbB1, TbB2;
    { const int b = 99 + 3*lane; TaB0 = pbB[b]; TaB1 = pbB[b+1]; TaB2 = pbB[b+2]; }
    if (hasB2) { const int b = 99 + 3*(64 + lane); TbB0 = pbB[b]; TbB1 = pbB[b+1]; TbB2 = pbB[b+2]; }

    // ---- phase B (LDS slice reuse is safe: same-wave DS ordering) ----
    sA4[lane] = hB0;
    if (lane < 35) sA4[64 + lane] = hB1;
    do_molecule(lane, sA[wid], sO[wid], obB, thB, TaB0, TaB1, TaB2, TbB0, TbB1, TbB2, hasB2);
}

extern "C" void kernel_launch(void* const* d_in, const int* in_sizes, int n_in,
                              void* d_out, int out_size, void* d_ws, size_t ws_size,
                              hipStream_t stream) {
    const float* theta = (const float*)d_in[0];  // input (N,K) fp32
    const float* pos0  = (const float*)d_in[1];  // pos0 (N,M,3) fp32
    float* out = (float*)d_out;                  // (N,M,3) fp32
    dihedral_pipe2_kernel<<<NMOL / (WPB * MPWAVE), TPB, 0, stream>>>(theta, pos0, out);
}

// Round 11
// 17.669 us; speedup vs baseline: 1.0733x; 1.0733x over previous
//
#include <hip/hip_runtime.h>

// Dihedral2Coord — TWO molecules per wave as two 32-lane segments.
// Lane sl of a segment owns steps 4sl..4sl+3 (atoms 4sl..4sl+6): serial
// pre-compose of 4 step-quats, 5-round width-32 shfl scan, 3 post-composes.
// Scan issue cost (the dominant VALU item) is per-wave -> amortized over 2
// molecules; bpermute count per molecule drops 49 -> 21.
//
// final[m] = P_{m-3}(pos0[m]); P_k = B_0∘...∘B_k (B_k applied FIRST),
// B_k = LOCAL-frame step rotation (dihedrals are rigid-invariant).

#define NK 128
#define NM 512
#define NMOL 4096
#define TPB 256
#define WPB 4        // waves per block
#define MPW 2        // molecules per wave (two 32-lane segments)
// grid = NMOL/(WPB*MPW) = 512

struct Aff { float qw, qx, qy, qz, tx, ty, tz; };

__device__ __forceinline__ void qrot(float qw, float qx, float qy, float qz,
                                     float vx, float vy, float vz,
                                     float& ox, float& oy, float& oz) {
    const float ux = qy*vz - qz*vy + qw*vx;
    const float uy = qz*vx - qx*vz + qw*vy;
    const float uz = qx*vy - qy*vx + qw*vz;
    ox = vx + 2.f*(qy*uz - qz*uy);
    oy = vy + 2.f*(qz*ux - qx*uz);
    oz = vz + 2.f*(qx*uy - qy*ux);
}

// (Q∘P)(x) = Q(P(x))
__device__ __forceinline__ Aff aff_compose(const Aff& Q, const Aff& P) {
    Aff r;
    r.qw = Q.qw*P.qw - Q.qx*P.qx - Q.qy*P.qy - Q.qz*P.qz;
    r.qx = Q.qw*P.qx + Q.qx*P.qw + Q.qy*P.qz - Q.qz*P.qy;
    r.qy = Q.qw*P.qy - Q.qx*P.qz + Q.qy*P.qw + Q.qz*P.qx;
    r.qz = Q.qw*P.qz + Q.qx*P.qy - Q.qy*P.qx + Q.qz*P.qw;
    float rx, ry, rz;
    qrot(Q.qw, Q.qx, Q.qy, Q.qz, P.tx, P.ty, P.tz, rx, ry, rz);
    r.tx = rx + Q.tx; r.ty = ry + Q.ty; r.tz = rz + Q.tz;
    return r;
}

#define SHFL_AFF_UP32(D, S, off)                                         \
    D.qw = __shfl_up(S.qw, off, 32); D.qx = __shfl_up(S.qx, off, 32);    \
    D.qy = __shfl_up(S.qy, off, 32); D.qz = __shfl_up(S.qz, off, 32);    \
    D.tx = __shfl_up(S.tx, off, 32); D.ty = __shfl_up(S.ty, off, 32);    \
    D.tz = __shfl_up(S.tz, off, 32);

// Build B_{4sl+j} from shared bonds/normals (j literal after unroll).
// sphi/cphi identical to the validated R10 formula.
#define BUILD_STEP(j, OUT) do {                                               \
    const float cxx = ny[(j)+1]*nz[(j)] - nz[(j)+1]*ny[(j)];                  \
    const float cxy = nz[(j)+1]*nx[(j)] - nx[(j)+1]*nz[(j)];                  \
    const float cxz = nx[(j)+1]*ny[(j)] - ny[(j)+1]*nx[(j)];                  \
    const float g   = cxx*vx[(j)+1] + cxy*vy[(j)+1] + cxz*vz[(j)+1];          \
    const float dnn = nx[(j)]*nx[(j)+1] + ny[(j)]*ny[(j)+1] + nz[(j)]*nz[(j)+1]; \
    const float r12 = rsqrtf(fmaxf(Ln[(j)]*Ln[(j)+1], 1e-30f));               \
    const float ira = rsqrtf(fmaxf(Lv[(j)+1], 1e-24f));                       \
    const float cphi = dnn*r12, sphi = g*r12*ira;                             \
    const float sth = __sinf(th[(j)]), cth = __cosf(th[(j)]);                 \
    const float c = cth*cphi - sth*sphi, s = sth*cphi + cth*sphi;             \
    const float hc = sqrtf(fmaxf(0.f, 0.5f*(1.f + c)));                       \
    const float hs = copysignf(sqrtf(fmaxf(0.f, 0.5f*(1.f - c))), s);         \
    const float hsa = hs*ira;                                                 \
    OUT.qw = hc; OUT.qx = vx[(j)+1]*hsa; OUT.qy = vy[(j)+1]*hsa; OUT.qz = vz[(j)+1]*hsa; \
    float rx, ry, rz;                                                         \
    qrot(OUT.qw, OUT.qx, OUT.qy, OUT.qz, A[3*(j)+3], A[3*(j)+4], A[3*(j)+5], rx, ry, rz); \
    OUT.tx = A[3*(j)+3]-rx; OUT.ty = A[3*(j)+4]-ry; OUT.tz = A[3*(j)+5]-rz;   \
} while (0)

__global__ __launch_bounds__(TPB, 2) void dihedral_seg2_kernel(
    const float* __restrict__ theta,  // (NMOL, NK)
    const float* __restrict__ pos0,   // (NMOL, NM, 3)
    float* __restrict__ out)          // (NMOL, NM, 3)
{
    const int tid  = threadIdx.x;
    const int lane = tid & 63;
    const int wid  = tid >> 6;
    const int seg  = lane >> 5;      // 0 or 1: which molecule of this wave
    const int sl   = lane & 31;      // segment-lane
    const int mol  = blockIdx.x * (WPB * MPW) + wid * MPW + seg;

    const float4* __restrict__ pb4 = (const float4*)(pos0 + (size_t)mol * (NM*3));
    float4*       __restrict__ ob4 = (float4*)(out  + (size_t)mol * (NM*3));

    __shared__ float sA[WPB][MPW][400];   // pos0 atoms 0..131 per molecule
    __shared__ float sO[WPB][MPW][400];   // final atoms 0..131

    // ---- issue ALL global loads up front (head 99 f4 + theta + 3 tail triples) ----
    const bool ex = (sl < 3);
    float4 h0 = pb4[sl], h1 = pb4[sl + 32], h2 = pb4[sl + 64];
    float4 h3; if (ex) h3 = pb4[96 + sl];
    const float4 th4 = ((const float4*)(theta + (size_t)mol * NK))[sl];
    float4 T0a, T0b, T0c, T1a, T1b, T1c, T2a, T2b, T2c;
    { const int b = 99 + 3*sl;        T0a = pb4[b]; T0b = pb4[b+1]; T0c = pb4[b+2]; }
    { const int b = 99 + 3*(sl + 32); T1a = pb4[b]; T1b = pb4[b+1]; T1c = pb4[b+2]; }
    const bool has3 = (sl < 31);      // triples 64..94
    if (has3) { const int b = 99 + 3*(sl + 64); T2a = pb4[b]; T2b = pb4[b+1]; T2c = pb4[b+2]; }

    // stage head into this segment's LDS slice (same-wave DS ordering, no barrier)
    float4* sA4 = (float4*)sA[wid][seg];
    sA4[sl] = h0; sA4[sl + 32] = h1; sA4[sl + 64] = h2;
    if (ex) sA4[96 + sl] = h3;

    // lane: atoms 4sl..4sl+6 (21 floats)
    float A[21];
    {
        const float2* ap2 = (const float2*)&sA[wid][seg][sl * 12];
        #pragma unroll
        for (int i = 0; i < 10; ++i) { const float2 v = ap2[i]; A[2*i] = v.x; A[2*i+1] = v.y; }
        A[20] = sA[wid][seg][sl * 12 + 20];
    }

    // shared bonds / normals / lengths for the 4 steps
    float vx[6], vy[6], vz[6];
    #pragma unroll
    for (int i = 0; i < 6; ++i) {
        vx[i] = A[3*i+3] - A[3*i];
        vy[i] = A[3*i+4] - A[3*i+1];
        vz[i] = A[3*i+5] - A[3*i+2];
    }
    float nx[5], ny[5], nz[5], Ln[5];
    #pragma unroll
    for (int i = 0; i < 5; ++i) {
        nx[i] = vy[i]*vz[i+1] - vz[i]*vy[i+1];
        ny[i] = vz[i]*vx[i+1] - vx[i]*vz[i+1];
        nz[i] = vx[i]*vy[i+1] - vy[i]*vx[i+1];
        Ln[i] = nx[i]*nx[i] + ny[i]*ny[i] + nz[i]*nz[i];
    }
    float Lv[5];
    #pragma unroll
    for (int i = 1; i < 5; ++i) Lv[i] = vx[i]*vx[i] + vy[i]*vy[i] + vz[i]*vz[i];
    const float th[4] = {th4.x, th4.y, th4.z, th4.w};

    // serial pre-compose: keep prefixes B0, C01, C012; S = D (4-step product)
    Aff B0;   BUILD_STEP(0, B0);
    Aff Bt;   BUILD_STEP(1, Bt);
    Aff C01  = aff_compose(B0, Bt);
    BUILD_STEP(2, Bt);
    Aff C012 = aff_compose(C01, Bt);
    BUILD_STEP(3, Bt);
    Aff S    = aff_compose(C012, Bt);

    // ---- 5-round width-32 inclusive scan: S -> D_0∘...∘D_sl ----
    #pragma unroll
    for (int off = 1; off < 32; off <<= 1) {
        Aff Q; SHFL_AFF_UP32(Q, S, off);
        if (sl >= off) S = aff_compose(Q, S);
    }
    // exclusive prefix
    Aff E; SHFL_AFF_UP32(E, S, 1);
    if (sl == 0) { E.qw = 1.f; E.qx = E.qy = E.qz = 0.f; E.tx = E.ty = E.tz = 0.f; }
    const Aff P0 = aff_compose(E, B0);    // P_{4sl}
    const Aff P1 = aff_compose(E, C01);   // P_{4sl+1}
    const Aff P2 = aff_compose(E, C012);  // P_{4sl+2}
    // P_{4sl+3} = S (inclusive)

    // ---- emit atoms 4sl+3..4sl+6 into sO ----
    {
        float ox, oy, oz;
        float* op = &sO[wid][seg][12*sl + 9];
        qrot(P0.qw, P0.qx, P0.qy, P0.qz, A[9],  A[10], A[11], ox, oy, oz);
        op[0] = ox + P0.tx; op[1] = oy + P0.ty; op[2] = oz + P0.tz;
        qrot(P1.qw, P1.qx, P1.qy, P1.qz, A[12], A[13], A[14], ox, oy, oz);
        op[3] = ox + P1.tx; op[4] = oy + P1.ty; op[5] = oz + P1.tz;
        qrot(P2.qw, P2.qx, P2.qy, P2.qz, A[15], A[16], A[17], ox, oy, oz);
        op[6] = ox + P2.tx; op[7] = oy + P2.ty; op[8] = oz + P2.tz;
        qrot(S.qw, S.qx, S.qy, S.qz, A[18], A[19], A[20], ox, oy, oz);
        op[9] = ox + S.tx;  op[10] = oy + S.ty; op[11] = oz + S.tz;
    }
    if (sl < 9) sO[wid][seg][sl] = sA[wid][seg][sl];   // atoms 0..2 never move
    if (sl == 31) {                                     // atom 131 = P_127(pos0[131])
        float ox, oy, oz;
        qrot(S.qw, S.qx, S.qy, S.qz, sA[wid][seg][393], sA[wid][seg][394], sA[wid][seg][395], ox, oy, oz);
        sO[wid][seg][393] = ox + S.tx; sO[wid][seg][394] = oy + S.ty; sO[wid][seg][395] = oz + S.tz;
    }

    // ---- F = P_127 broadcast from segment-lane 31 (width-32 shfl) ----
    Aff F;
    F.qw = __shfl(S.qw, 31, 32); F.qx = __shfl(S.qx, 31, 32);
    F.qy = __shfl(S.qy, 31, 32); F.qz = __shfl(S.qz, 31, 32);
    F.tx = __shfl(S.tx, 31, 32); F.ty = __shfl(S.ty, 31, 32);
    F.tz = __shfl(S.tz, 31, 32);
    const float f00 = 1.f - 2.f*(F.qy*F.qy + F.qz*F.qz);
    const float f01 = 2.f*(F.qx*F.qy - F.qw*F.qz);
    const float f02 = 2.f*(F.qx*F.qz + F.qw*F.qy);
    const float f10 = 2.f*(F.qx*F.qy + F.qw*F.qz);
    const float f11 = 1.f - 2.f*(F.qx*F.qx + F.qz*F.qz);
    const float f12 = 2.f*(F.qy*F.qz - F.qw*F.qx);
    const float f20 = 2.f*(F.qx*F.qz - F.qw*F.qy);
    const float f21 = 2.f*(F.qy*F.qz + F.qw*F.qx);
    const float f22 = 1.f - 2.f*(F.qx*F.qx + F.qy*F.qy);

    // ---- store head (99 f4 per segment) ----
    const float4* sO4 = (const float4*)sO[wid][seg];
    ob4[sl] = sO4[sl]; ob4[sl + 32] = sO4[sl + 32]; ob4[sl + 64] = sO4[sl + 64];
    if (ex) ob4[96 + sl] = sO4[96 + sl];

    // ---- tail: 95 f4-triples per molecule, 3 per lane, data in registers ----
    #define TAIL_EMIT(b, va, vb, vc)                                          \
    do {                                                                      \
        const float x0=va.x, y0=va.y, z0=va.z;                                \
        const float x1=va.w, y1=vb.x, z1=vb.y;                                \
        const float x2=vb.z, y2=vb.w, z2=vc.x;                                \
        const float x3=vc.y, y3=vc.z, z3=vc.w;                                \
        float4 o0, o1, o2;                                                    \
        o0.x = f00*x0+f01*y0+f02*z0+F.tx; o0.y = f10*x0+f11*y0+f12*z0+F.ty;   \
        o0.z = f20*x0+f21*y0+f22*z0+F.tz; o0.w = f00*x1+f01*y1+f02*z1+F.tx;   \
        o1.x = f10*x1+f11*y1+f12*z1+F.ty; o1.y = f20*x1+f21*y1+f22*z1+F.tz;   \
        o1.z = f00*x2+f01*y2+f02*z2+F.tx; o1.w = f10*x2+f11*y2+f12*z2+F.ty;   \
        o2.x = f20*x2+f21*y2+f22*z2+F.tz; o2.y = f00*x3+f01*y3+f02*z3+F.tx;   \
        o2.z = f10*x3+f11*y3+f12*z3+F.ty; o2.w = f20*x3+f21*y3+f22*z3+F.tz;   \
        ob4[(b)] = o0; ob4[(b)+1] = o1; ob4[(b)+2] = o2;                      \
    } while (0)

    TAIL_EMIT(99 + 3*sl,        T0a, T0b, T0c);
    TAIL_EMIT(99 + 3*(sl + 32), T1a, T1b, T1c);
    if (has3) TAIL_EMIT(99 + 3*(sl + 64), T2a, T2b, T2c);
    #undef TAIL_EMIT
}

extern "C" void kernel_launch(void* const* d_in, const int* in_sizes, int n_in,
                              void* d_out, int out_size, void* d_ws, size_t ws_size,
                              hipStream_t stream) {
    const float* theta = (const float*)d_in[0];  // input (N,K) fp32
    const float* pos0  = (const float*)d_in[1];  // pos0 (N,M,3) fp32
    float* out = (float*)d_out;                  // (N,M,3) fp32
    dihedral_seg2_kernel<<<NMOL / (WPB * MPW), TPB, 0, stream>>>(theta, pos0, out);
}